// Round 2
// baseline (266.708 us; speedup 1.0000x reference)
//
#include <hip/hip_runtime.h>

// QRNN: B=8 T=2048 C=512 U=512 W=2
// R2 changes vs R1:
//  - gemm: A fragments loaded direct from global (register prefetch, no LDS);
//          B LDS double-buffered, staged 1 iter ahead -> 1 barrier/iter, no hot drain;
//          quad-major LDS layout [kquad][row][16B] -> 2-way (free) bank access.
//  - scan: NC 32->64, CL 64->32 (2 blocks/CU for phases A/C).

#define Bn 8
#define Tn 2048
#define Cn 512
#define Un 512
#define Nn 1536
#define Kn 1024
#define Mn (Bn * Tn)
#define NC 64   // chunks per sequence
#define CL 32   // chunk length (NC*CL == Tn)

using bf16x8 = __attribute__((ext_vector_type(8))) __bf16;
using f32x4  = __attribute__((ext_vector_type(4))) float;

__device__ __forceinline__ void async16(const void* g, void* l) {
  __builtin_amdgcn_global_load_lds((const __attribute__((address_space(1))) void*)g,
                                   (__attribute__((address_space(3))) void*)l, 16, 0, 0);
}

__device__ __forceinline__ unsigned short f2bf(float v) {
  union { float f; unsigned u; } c; c.f = v;
  unsigned u = c.u;
  return (unsigned short)((u + 0x7fffu + ((u >> 16) & 1u)) >> 16);  // RNE
}

__device__ __forceinline__ float fast_sigmoid(float x) {
  float e = __builtin_amdgcn_exp2f(-1.4426950408889634f * x);
  return __builtin_amdgcn_rcpf(1.0f + e);
}
__device__ __forceinline__ float fast_tanh(float x) {
  float e = __builtin_amdgcn_exp2f(-2.8853900817779268f * x);
  return 2.0f * __builtin_amdgcn_rcpf(1.0f + e) - 1.0f;
}

// ---- 1. x -> padded bf16 ----------------------------------------------------
__global__ __launch_bounds__(256) void conv_x(const float* __restrict__ x,
                                              unsigned short* __restrict__ xb) {
  int idx = blockIdx.x * 256 + threadIdx.x;   // over B*(T+1)*C/4
  int c4  = idx & 127;                        // C/4 = 128
  int row = idx >> 7;                         // b*(T+1)+t
  int b   = row / (Tn + 1);
  int t   = row - b * (Tn + 1);
  ushort4 ov;
  if (t == 0) {
    ov.x = ov.y = ov.z = ov.w = 0;
  } else {
    float4 v = *(const float4*)(x + (size_t)(b * Tn + t - 1) * Cn + c4 * 4);
    ov.x = f2bf(v.x); ov.y = f2bf(v.y); ov.z = f2bf(v.z); ov.w = f2bf(v.w);
  }
  *(ushort4*)(xb + (size_t)row * Cn + c4 * 4) = ov;
}

// ---- 2. kernel -> bf16 transposed [N][K] ------------------------------------
__global__ __launch_bounds__(256) void conv_k(const float* __restrict__ kern,
                                              unsigned short* __restrict__ kT) {
  __shared__ float tile[32][33];
  int kb = blockIdx.x, nb = blockIdx.y;       // grid (32, 48)
  int tx = threadIdx.x & 31, ty = threadIdx.x >> 5;
#pragma unroll
  for (int i = 0; i < 4; i++)
    tile[ty + i * 8][tx] = kern[(size_t)(kb * 32 + ty + i * 8) * Nn + nb * 32 + tx];
  __syncthreads();
#pragma unroll
  for (int i = 0; i < 4; i++) {
    int n = nb * 32 + ty + i * 8;
    int k = kb * 32 + tx;
    kT[(size_t)n * Kn + k] = f2bf(tile[tx][ty + i * 8]);
  }
}

// ---- 3. MFMA GEMM + activation epilogue -------------------------------------
// Block tile 128x128, 4 waves (2x2 of 64x64). A: direct global frag loads,
// register-prefetched. B: LDS double-buffer, quad-major [q][row][8 shorts].
__global__ __launch_bounds__(256) void gemm_gates(const unsigned short* __restrict__ xb,
                                                  const unsigned short* __restrict__ kT,
                                                  const float* __restrict__ bias,
                                                  float* __restrict__ gates) {
  __shared__ unsigned short Bs[2][4096];    // 2 x 8KB, layout q*1024 + row*8 (shorts)
  const int tid = threadIdx.x;
  const int m0 = blockIdx.x * 128;
  const int n0 = blockIdx.y * 128;
  const int batch = m0 / Tn;                // tiles never cross batch
  const int lane = tid & 63;
  const int w = tid >> 6, wr = w >> 1, wc = w & 1;

  // B staging: call1 covers slots tid (q=tid>>7, r=tid&127), call2 slots 256+tid.
  const unsigned short* bRow = kT + (size_t)(n0 + (tid & 127)) * Kn + (tid >> 7) * 8;

  // A frag base: lane -> row (lane&15), kquad (lane>>4)
  const unsigned short* aBase = xb + (size_t)(m0 + batch + wr * 64 + (lane & 15)) * Cn
                                   + (lane >> 4) * 8;
  // B frag base in LDS (shorts): quad (lane>>4)*1024 + row*8
  const int bOff = (lane >> 4) * 1024 + (wc * 64 + (lane & 15)) * 8;

  f32x4 zero = {0.f, 0.f, 0.f, 0.f};
  f32x4 acc[4][4];
#pragma unroll
  for (int i = 0; i < 4; i++)
#pragma unroll
    for (int j = 0; j < 4; j++) acc[i][j] = zero;

  // prologue: stage B k0=0 into buf0; preload A frags k0=0
  async16(bRow, &Bs[0][tid * 8]);
  async16(bRow + 16, &Bs[0][2048 + tid * 8]);
  bf16x8 afc[4], afn[4];
#pragma unroll
  for (int i = 0; i < 4; i++) afc[i] = *(const bf16x8*)(aBase + (size_t)i * 16 * Cn);

  for (int k0 = 0; k0 < Kn; k0 += 32) {
    const int buf = (k0 >> 5) & 1;
    __syncthreads();   // per-wave vmcnt drain covers staging issued LAST iter
    if (k0 + 32 < Kn) {
      async16(bRow + k0 + 32, &Bs[buf ^ 1][tid * 8]);
      async16(bRow + k0 + 48, &Bs[buf ^ 1][2048 + tid * 8]);
#pragma unroll
      for (int i = 0; i < 4; i++)
        afn[i] = *(const bf16x8*)(aBase + (size_t)i * 16 * Cn + k0 + 32);
    }
    bf16x8 bfr[4];
#pragma unroll
    for (int j = 0; j < 4; j++) bfr[j] = *(const bf16x8*)&Bs[buf][bOff + j * 16 * 8];
#pragma unroll
    for (int i = 0; i < 4; i++)
#pragma unroll
      for (int j = 0; j < 4; j++)
        acc[i][j] = __builtin_amdgcn_mfma_f32_16x16x32_bf16(afc[i], bfr[j], acc[i][j], 0, 0, 0);
#pragma unroll
    for (int i = 0; i < 4; i++) afc[i] = afn[i];
  }

  // epilogue: C/D layout col=lane&15 (N), row=(lane>>4)*4+r (M)
  const int region = blockIdx.y >> 2;       // 0=z(tanh) 1=f(sig) 2=o(sig)
  const int rowB = wr * 64 + (lane >> 4) * 4;
  const int colB = wc * 64 + (lane & 15);
#pragma unroll
  for (int i = 0; i < 4; i++)
#pragma unroll
    for (int j = 0; j < 4; j++)
#pragma unroll
      for (int r = 0; r < 4; r++) {
        int mm = m0 + rowB + i * 16 + r;
        int nn = n0 + colB + j * 16;
        float g = acc[i][j][r] + bias[nn];
        float a = (region == 0) ? fast_tanh(g) : fast_sigmoid(g);
        gates[(size_t)mm * Nn + nn] = a;
      }
}

// ---- 4. per-chunk affine (a, bv): h_end = a*h_start + bv --------------------
__global__ __launch_bounds__(512) void scan_phaseA(const float* __restrict__ gates,
                                                   float* __restrict__ aArr,
                                                   float* __restrict__ bArr) {
  int u = threadIdx.x;
  int blk = blockIdx.x;                     // b*NC + c
  int b = blk >> 6, c = blk & (NC - 1);
  const float* gp = gates + (size_t)(b * Tn + c * CL) * Nn;
  float a = 1.0f, bv = 0.0f;
#pragma unroll 8
  for (int t = 0; t < CL; t++) {
    float z = gp[u];
    float f = gp[Un + u];
    a *= f;
    bv = f * bv + (1.0f - f) * z;
    gp += Nn;
  }
  aArr[(size_t)blk * Un + u] = a;
  bArr[(size_t)blk * Un + u] = bv;
}

// ---- 5. scan over chunks ----------------------------------------------------
__global__ __launch_bounds__(256) void scan_phaseB(const float* __restrict__ aArr,
                                                   const float* __restrict__ bArr,
                                                   const float* __restrict__ init,
                                                   float* __restrict__ hstart) {
  int idx = blockIdx.x * 256 + threadIdx.x; // 0..4095 = (b,u)
  int b = idx >> 9, u = idx & (Un - 1);
  float h = init[u];
  for (int c = 0; c < NC; c++) {
    size_t offc = (size_t)(b * NC + c) * Un + u;
    hstart[offc] = h;
    h = aArr[offc] * h + bArr[offc];
  }
}

// ---- 6. replay chunk with known h_start, apply output gate ------------------
__global__ __launch_bounds__(512) void scan_phaseC(const float* __restrict__ gates,
                                                   const float* __restrict__ hstart,
                                                   float* __restrict__ out) {
  int u = threadIdx.x;
  int blk = blockIdx.x;
  int b = blk >> 6, c = blk & (NC - 1);
  const float* gp = gates + (size_t)(b * Tn + c * CL) * Nn;
  float* op = out + (size_t)(b * Tn + c * CL) * Un;
  float h = hstart[(size_t)blk * Un + u];
#pragma unroll 8
  for (int t = 0; t < CL; t++) {
    float z = gp[u];
    float f = gp[Un + u];
    float o = gp[2 * Un + u];
    h = f * h + (1.0f - f) * z;
    op[u] = h * o;
    gp += Nn;
    op += Un;
  }
}

extern "C" void kernel_launch(void* const* d_in, const int* in_sizes, int n_in,
                              void* d_out, int out_size, void* d_ws, size_t ws_size,
                              hipStream_t stream) {
  const float* x    = (const float*)d_in[0];  // [8,2048,512]
  const float* kern = (const float*)d_in[1];  // [2,512,1536]
  const float* bias = (const float*)d_in[2];  // [1536]
  const float* init = (const float*)d_in[3];  // [1,512]
  float* out = (float*)d_out;                 // [8,2048,512]

  char* ws = (char*)d_ws;
  unsigned short* xb = (unsigned short*)ws;                      // 16.8 MB
  size_t off = (size_t)Bn * (Tn + 1) * Cn * 2;
  unsigned short* kT = (unsigned short*)(ws + off);              // 3.1 MB
  off += (size_t)Nn * Kn * 2;
  float* gates = (float*)(ws + off);                             // 100.7 MB
  off += (size_t)Mn * Nn * 4;
  float* aArr = (float*)(ws + off);  off += (size_t)Bn * NC * Un * 4;
  float* bArr = (float*)(ws + off);  off += (size_t)Bn * NC * Un * 4;
  float* hstart = (float*)(ws + off);

  conv_x<<<(Bn * (Tn + 1) * Cn / 4) / 256, 256, 0, stream>>>(x, xb);
  conv_k<<<dim3(32, 48), 256, 0, stream>>>(kern, kT);
  gemm_gates<<<dim3(Mn / 128, Nn / 128), 256, 0, stream>>>(xb, kT, bias, gates);
  scan_phaseA<<<Bn * NC, 512, 0, stream>>>(gates, aArr, bArr);
  scan_phaseB<<<(Bn * Un) / 256, 256, 0, stream>>>(aArr, bArr, init, hstart);
  scan_phaseC<<<Bn * NC, 512, 0, stream>>>(gates, hstart, out);
}

// Round 3
// 187.684 us; speedup vs baseline: 1.4210x; 1.4210x over previous
//
#include <hip/hip_runtime.h>

// QRNN: B=8 T=2048 C=512 U=512 W=2
// R3: gemm reverted to all-LDS staging (R1 topology) with
//   - BK=64 (16 K-iters, 32 MFMAs per stage, halved barrier count)
//   - XOR-swizzled LDS layout: frag [row][kq] at col' = kq ^ (row&7)
//     -> staging stays coalesced (8 lanes cover one row's 128B, permuted)
//     -> ds_read_b128: 16 rows hit 8 distinct 16B columns = 32 banks 2-way (free)
//   - scan phases float4-vectorized.

#define Bn 8
#define Tn 2048
#define Cn 512
#define Un 512
#define Nn 1536
#define Kn 1024
#define Mn (Bn * Tn)
#define NC 64   // chunks per sequence
#define CL 32   // chunk length (NC*CL == Tn)

using bf16x8 = __attribute__((ext_vector_type(8))) __bf16;
using f32x4  = __attribute__((ext_vector_type(4))) float;

__device__ __forceinline__ void async16(const void* g, void* l) {
  __builtin_amdgcn_global_load_lds((const __attribute__((address_space(1))) void*)g,
                                   (__attribute__((address_space(3))) void*)l, 16, 0, 0);
}

__device__ __forceinline__ unsigned short f2bf(float v) {
  union { float f; unsigned u; } c; c.f = v;
  unsigned u = c.u;
  return (unsigned short)((u + 0x7fffu + ((u >> 16) & 1u)) >> 16);  // RNE
}

__device__ __forceinline__ float fast_sigmoid(float x) {
  float e = __builtin_amdgcn_exp2f(-1.4426950408889634f * x);
  return __builtin_amdgcn_rcpf(1.0f + e);
}
__device__ __forceinline__ float fast_tanh(float x) {
  float e = __builtin_amdgcn_exp2f(-2.8853900817779268f * x);
  return 2.0f * __builtin_amdgcn_rcpf(1.0f + e) - 1.0f;
}

// ---- 1. x -> padded bf16 ----------------------------------------------------
__global__ __launch_bounds__(256) void conv_x(const float* __restrict__ x,
                                              unsigned short* __restrict__ xb) {
  int idx = blockIdx.x * 256 + threadIdx.x;   // over B*(T+1)*C/4
  int c4  = idx & 127;                        // C/4 = 128
  int row = idx >> 7;                         // b*(T+1)+t
  int b   = row / (Tn + 1);
  int t   = row - b * (Tn + 1);
  ushort4 ov;
  if (t == 0) {
    ov.x = ov.y = ov.z = ov.w = 0;
  } else {
    float4 v = *(const float4*)(x + (size_t)(b * Tn + t - 1) * Cn + c4 * 4);
    ov.x = f2bf(v.x); ov.y = f2bf(v.y); ov.z = f2bf(v.z); ov.w = f2bf(v.w);
  }
  *(ushort4*)(xb + (size_t)row * Cn + c4 * 4) = ov;
}

// ---- 2. kernel -> bf16 transposed [N][K] ------------------------------------
__global__ __launch_bounds__(256) void conv_k(const float* __restrict__ kern,
                                              unsigned short* __restrict__ kT) {
  __shared__ float tile[32][33];
  int kb = blockIdx.x, nb = blockIdx.y;       // grid (32, 48)
  int tx = threadIdx.x & 31, ty = threadIdx.x >> 5;
#pragma unroll
  for (int i = 0; i < 4; i++)
    tile[ty + i * 8][tx] = kern[(size_t)(kb * 32 + ty + i * 8) * Nn + nb * 32 + tx];
  __syncthreads();
#pragma unroll
  for (int i = 0; i < 4; i++) {
    int n = nb * 32 + ty + i * 8;
    int k = kb * 32 + tx;
    kT[(size_t)n * Kn + k] = f2bf(tile[tx][ty + i * 8]);
  }
}

// ---- 3. MFMA GEMM + activation epilogue -------------------------------------
// Block tile 128x128, BK=64, 4 waves (2x2 of 64x64).
// LDS: As/Bs [128 rows][64 shorts], frag [row][kq] stored at 16B-col kq^(row&7).
__global__ __launch_bounds__(256) void gemm_gates(const unsigned short* __restrict__ xb,
                                                  const unsigned short* __restrict__ kT,
                                                  const float* __restrict__ bias,
                                                  float* __restrict__ gates) {
  __shared__ unsigned short As[128 * 64];   // 16 KB
  __shared__ unsigned short Bs[128 * 64];   // 16 KB
  const int tid = threadIdx.x;
  const int m0 = blockIdx.x * 128;
  const int n0 = blockIdx.y * 128;
  const int batch = m0 / Tn;                // tiles never cross batch
  const int lane = tid & 63;
  const int w = tid >> 6, wr = w >> 1, wc = w & 1;

  // Staging: call j covers LDS 16B-slots [j*256 + tid]; slot s -> row=s>>3, kcol=s&7.
  // Slot (row,kcol) holds frag kq' = kcol ^ (row&7); row&7 == lane>>3, kcol == lane&7.
  const int srow = (w << 3) + (lane >> 3);        // + j*32 per call
  const int skq  = (lane & 7) ^ (lane >> 3);      // frag index this lane fetches
  const unsigned short* aStage = xb + (size_t)(m0 + batch + srow) * Cn + (skq << 3);
  const unsigned short* bStage = kT + (size_t)(n0 + srow) * Kn + (skq << 3);

  f32x4 zero = {0.f, 0.f, 0.f, 0.f};
  f32x4 acc[4][4];
#pragma unroll
  for (int i = 0; i < 4; i++)
#pragma unroll
    for (int j = 0; j < 4; j++) acc[i][j] = zero;

  const int rA0 = wr * 64 + (lane & 15);    // frag row base for A reads
  const int rB0 = wc * 64 + (lane & 15);
  const int swz = lane & 7;                 // row&7 for frag reads

  for (int k0 = 0; k0 < Kn; k0 += 64) {
#pragma unroll
    for (int j = 0; j < 4; j++) {
      async16(aStage + (size_t)(j << 5) * Cn + k0, &As[(j * 256 + tid) * 8]);
      async16(bStage + (size_t)(j << 5) * Kn + k0, &Bs[(j * 256 + tid) * 8]);
    }
    __builtin_amdgcn_s_waitcnt(0);
    __syncthreads();

#pragma unroll
    for (int ks = 0; ks < 2; ks++) {
      const int col = (((ks << 2) + (lane >> 4)) ^ swz) << 3;  // swizzled 16B col (shorts)
      bf16x8 af[4], bf[4];
#pragma unroll
      for (int i = 0; i < 4; i++) {
        af[i] = *(const bf16x8*)&As[(rA0 + i * 16) * 64 + col];
        bf[i] = *(const bf16x8*)&Bs[(rB0 + i * 16) * 64 + col];
      }
#pragma unroll
      for (int i = 0; i < 4; i++)
#pragma unroll
        for (int j = 0; j < 4; j++)
          acc[i][j] = __builtin_amdgcn_mfma_f32_16x16x32_bf16(af[i], bf[j], acc[i][j], 0, 0, 0);
    }
    __syncthreads();
  }

  // epilogue: C/D layout col=lane&15 (N), row=(lane>>4)*4+r (M)
  const int region = blockIdx.y >> 2;       // 0=z(tanh) 1=f(sig) 2=o(sig)
  const int rowB = wr * 64 + (lane >> 4) * 4;
  const int colB = wc * 64 + (lane & 15);
#pragma unroll
  for (int i = 0; i < 4; i++)
#pragma unroll
    for (int j = 0; j < 4; j++)
#pragma unroll
      for (int r = 0; r < 4; r++) {
        int mm = m0 + rowB + i * 16 + r;
        int nn = n0 + colB + j * 16;
        float g = acc[i][j][r] + bias[nn];
        float a = (region == 0) ? fast_tanh(g) : fast_sigmoid(g);
        gates[(size_t)mm * Nn + nn] = a;
      }
}

// ---- 4. per-chunk affine (a, bv): h_end = a*h_start + bv --------------------
__global__ __launch_bounds__(128) void scan_phaseA(const float* __restrict__ gates,
                                                   float* __restrict__ aArr,
                                                   float* __restrict__ bArr) {
  int u4 = threadIdx.x * 4;
  int blk = blockIdx.x;                     // chunk id: b*NC + c
  int b = blk >> 6, c = blk & (NC - 1);
  const float* gp = gates + (size_t)(b * Tn + c * CL) * Nn;
  float4 a = {1.f, 1.f, 1.f, 1.f}, bv = {0.f, 0.f, 0.f, 0.f};
#pragma unroll 4
  for (int t = 0; t < CL; t++) {
    float4 z = *(const float4*)(gp + u4);
    float4 f = *(const float4*)(gp + Un + u4);
    a.x *= f.x; a.y *= f.y; a.z *= f.z; a.w *= f.w;
    bv.x = f.x * bv.x + (1.0f - f.x) * z.x;
    bv.y = f.y * bv.y + (1.0f - f.y) * z.y;
    bv.z = f.z * bv.z + (1.0f - f.z) * z.z;
    bv.w = f.w * bv.w + (1.0f - f.w) * z.w;
    gp += Nn;
  }
  *(float4*)(aArr + (size_t)blk * Un + u4) = a;
  *(float4*)(bArr + (size_t)blk * Un + u4) = bv;
}

// ---- 5. scan over chunks ----------------------------------------------------
__global__ __launch_bounds__(256) void scan_phaseB(const float* __restrict__ aArr,
                                                   const float* __restrict__ bArr,
                                                   const float* __restrict__ init,
                                                   float* __restrict__ hstart) {
  int idx = blockIdx.x * 256 + threadIdx.x; // 0..4095 = (b,u)
  int b = idx >> 9, u = idx & (Un - 1);
  float h = init[u];
  for (int c = 0; c < NC; c++) {
    size_t offc = (size_t)(b * NC + c) * Un + u;
    hstart[offc] = h;
    h = aArr[offc] * h + bArr[offc];
  }
}

// ---- 6. replay chunk with known h_start, apply output gate ------------------
__global__ __launch_bounds__(128) void scan_phaseC(const float* __restrict__ gates,
                                                   const float* __restrict__ hstart,
                                                   float* __restrict__ out) {
  int u4 = threadIdx.x * 4;
  int blk = blockIdx.x;
  int b = blk >> 6, c = blk & (NC - 1);
  const float* gp = gates + (size_t)(b * Tn + c * CL) * Nn;
  float* op = out + (size_t)(b * Tn + c * CL) * Un;
  float4 h = *(const float4*)(hstart + (size_t)blk * Un + u4);
#pragma unroll 4
  for (int t = 0; t < CL; t++) {
    float4 z = *(const float4*)(gp + u4);
    float4 f = *(const float4*)(gp + Un + u4);
    float4 o = *(const float4*)(gp + 2 * Un + u4);
    h.x = f.x * h.x + (1.0f - f.x) * z.x;
    h.y = f.y * h.y + (1.0f - f.y) * z.y;
    h.z = f.z * h.z + (1.0f - f.z) * z.z;
    h.w = f.w * h.w + (1.0f - f.w) * z.w;
    float4 ov;
    ov.x = h.x * o.x; ov.y = h.y * o.y; ov.z = h.z * o.z; ov.w = h.w * o.w;
    *(float4*)(op + u4) = ov;
    gp += Nn;
    op += Un;
  }
}

extern "C" void kernel_launch(void* const* d_in, const int* in_sizes, int n_in,
                              void* d_out, int out_size, void* d_ws, size_t ws_size,
                              hipStream_t stream) {
  const float* x    = (const float*)d_in[0];  // [8,2048,512]
  const float* kern = (const float*)d_in[1];  // [2,512,1536]
  const float* bias = (const float*)d_in[2];  // [1536]
  const float* init = (const float*)d_in[3];  // [1,512]
  float* out = (float*)d_out;                 // [8,2048,512]

  char* ws = (char*)d_ws;
  unsigned short* xb = (unsigned short*)ws;                      // 16.8 MB
  size_t off = (size_t)Bn * (Tn + 1) * Cn * 2;
  unsigned short* kT = (unsigned short*)(ws + off);              // 3.1 MB
  off += (size_t)Nn * Kn * 2;
  float* gates = (float*)(ws + off);                             // 100.7 MB
  off += (size_t)Mn * Nn * 4;
  float* aArr = (float*)(ws + off);  off += (size_t)Bn * NC * Un * 4;
  float* bArr = (float*)(ws + off);  off += (size_t)Bn * NC * Un * 4;
  float* hstart = (float*)(ws + off);

  conv_x<<<(Bn * (Tn + 1) * Cn / 4) / 256, 256, 0, stream>>>(x, xb);
  conv_k<<<dim3(32, 48), 256, 0, stream>>>(kern, kT);
  gemm_gates<<<dim3(Mn / 128, Nn / 128), 256, 0, stream>>>(xb, kT, bias, gates);
  scan_phaseA<<<Bn * NC, 128, 0, stream>>>(gates, aArr, bArr);
  scan_phaseB<<<(Bn * Un) / 256, 256, 0, stream>>>(aArr, bArr, init, hstart);
  scan_phaseC<<<Bn * NC, 128, 0, stream>>>(gates, hstart, out);
}

// Round 5
// 175.781 us; speedup vs baseline: 1.5173x; 1.0677x over previous
//
#include <hip/hip_runtime.h>

// QRNN: B=8 T=2048 C=512 U=512 W=2
// R5 = proven components + bf16 gates:
//  - gemm: EXACT R3 structure (16x16x32 MFMA, 128x128 tile, BK=64, XOR swizzle,
//    passed full harness at 68 us) -- only change: epilogue stores bf16 gates.
//  - scan: R1 trio (NC=32, phaseA/B/C) -- phaseA/C split in u into 2 half-blocks
//    (512 blocks x 256 thr), reading bf16 gates.
//  - gates bf16 halves the dominant HBM traffic (~130 MB saved).

#define Bn 8
#define Tn 2048
#define Cn 512
#define Un 512
#define Nn 1536
#define Kn 1024
#define Mn (Bn * Tn)
#define NC 32   // chunks per sequence
#define CL 64   // chunk length (NC*CL == Tn)

using bf16x8 = __attribute__((ext_vector_type(8))) __bf16;
using f32x4  = __attribute__((ext_vector_type(4))) float;

__device__ __forceinline__ void async16(const void* g, void* l) {
  __builtin_amdgcn_global_load_lds((const __attribute__((address_space(1))) void*)g,
                                   (__attribute__((address_space(3))) void*)l, 16, 0, 0);
}

__device__ __forceinline__ unsigned short f2bf(float v) {
  union { float f; unsigned u; } c; c.f = v;
  unsigned u = c.u;
  return (unsigned short)((u + 0x7fffu + ((u >> 16) & 1u)) >> 16);  // RNE
}

__device__ __forceinline__ float bf2f(unsigned short h) {
  union { unsigned u; float f; } c; c.u = ((unsigned)h) << 16;
  return c.f;
}

__device__ __forceinline__ float fast_sigmoid(float x) {
  float e = __builtin_amdgcn_exp2f(-1.4426950408889634f * x);
  return __builtin_amdgcn_rcpf(1.0f + e);
}
__device__ __forceinline__ float fast_tanh(float x) {
  float e = __builtin_amdgcn_exp2f(-2.8853900817779268f * x);
  return 2.0f * __builtin_amdgcn_rcpf(1.0f + e) - 1.0f;
}

// ---- 1. x -> padded bf16 ----------------------------------------------------
__global__ __launch_bounds__(256) void conv_x(const float* __restrict__ x,
                                              unsigned short* __restrict__ xb) {
  int idx = blockIdx.x * 256 + threadIdx.x;   // over B*(T+1)*C/4
  int c4  = idx & 127;                        // C/4 = 128
  int row = idx >> 7;                         // b*(T+1)+t
  int b   = row / (Tn + 1);
  int t   = row - b * (Tn + 1);
  ushort4 ov;
  if (t == 0) {
    ov.x = ov.y = ov.z = ov.w = 0;
  } else {
    float4 v = *(const float4*)(x + (size_t)(b * Tn + t - 1) * Cn + c4 * 4);
    ov.x = f2bf(v.x); ov.y = f2bf(v.y); ov.z = f2bf(v.z); ov.w = f2bf(v.w);
  }
  *(ushort4*)(xb + (size_t)row * Cn + c4 * 4) = ov;
}

// ---- 2. kernel -> bf16 transposed [N][K] ------------------------------------
__global__ __launch_bounds__(256) void conv_k(const float* __restrict__ kern,
                                              unsigned short* __restrict__ kT) {
  __shared__ float tile[32][33];
  int kb = blockIdx.x, nb = blockIdx.y;       // grid (32, 48)
  int tx = threadIdx.x & 31, ty = threadIdx.x >> 5;
#pragma unroll
  for (int i = 0; i < 4; i++)
    tile[ty + i * 8][tx] = kern[(size_t)(kb * 32 + ty + i * 8) * Nn + nb * 32 + tx];
  __syncthreads();
#pragma unroll
  for (int i = 0; i < 4; i++) {
    int n = nb * 32 + ty + i * 8;
    int k = kb * 32 + tx;
    kT[(size_t)n * Kn + k] = f2bf(tile[tx][ty + i * 8]);
  }
}

// ---- 3. MFMA GEMM + activation epilogue (R3 structure, bf16 output) ---------
// Block tile 128x128, BK=64, 4 waves (2x2 of 64x64).
// LDS: As/Bs [128 rows][64 shorts], frag [row][kq] stored at 16B-col kq^(row&7).
__global__ __launch_bounds__(256) void gemm_gates(const unsigned short* __restrict__ xb,
                                                  const unsigned short* __restrict__ kT,
                                                  const float* __restrict__ bias,
                                                  unsigned short* __restrict__ gates) {
  __shared__ unsigned short As[128 * 64];   // 16 KB
  __shared__ unsigned short Bs[128 * 64];   // 16 KB
  const int tid = threadIdx.x;
  const int m0 = blockIdx.x * 128;
  const int n0 = blockIdx.y * 128;
  const int batch = m0 / Tn;                // tiles never cross batch
  const int lane = tid & 63;
  const int w = tid >> 6, wr = w >> 1, wc = w & 1;

  // Staging: call j covers LDS 16B-slots [j*256 + tid]; slot s -> row=s>>3, kcol=s&7.
  // Slot (row,kcol) holds frag kq' = kcol ^ (row&7); row&7 == lane>>3, kcol == lane&7.
  const int srow = (w << 3) + (lane >> 3);        // + j*32 per call
  const int skq  = (lane & 7) ^ (lane >> 3);      // frag index this lane fetches
  const unsigned short* aStage = xb + (size_t)(m0 + batch + srow) * Cn + (skq << 3);
  const unsigned short* bStage = kT + (size_t)(n0 + srow) * Kn + (skq << 3);

  f32x4 zero = {0.f, 0.f, 0.f, 0.f};
  f32x4 acc[4][4];
#pragma unroll
  for (int i = 0; i < 4; i++)
#pragma unroll
    for (int j = 0; j < 4; j++) acc[i][j] = zero;

  const int rA0 = wr * 64 + (lane & 15);    // frag row base for A reads
  const int rB0 = wc * 64 + (lane & 15);
  const int swz = lane & 7;                 // row&7 for frag reads

  for (int k0 = 0; k0 < Kn; k0 += 64) {
#pragma unroll
    for (int j = 0; j < 4; j++) {
      async16(aStage + (size_t)(j << 5) * Cn + k0, &As[(j * 256 + tid) * 8]);
      async16(bStage + (size_t)(j << 5) * Kn + k0, &Bs[(j * 256 + tid) * 8]);
    }
    __builtin_amdgcn_s_waitcnt(0);
    __syncthreads();

#pragma unroll
    for (int ks = 0; ks < 2; ks++) {
      const int col = (((ks << 2) + (lane >> 4)) ^ swz) << 3;  // swizzled 16B col (shorts)
      bf16x8 af[4], bf[4];
#pragma unroll
      for (int i = 0; i < 4; i++) {
        af[i] = *(const bf16x8*)&As[(rA0 + i * 16) * 64 + col];
        bf[i] = *(const bf16x8*)&Bs[(rB0 + i * 16) * 64 + col];
      }
#pragma unroll
      for (int i = 0; i < 4; i++)
#pragma unroll
        for (int j = 0; j < 4; j++)
          acc[i][j] = __builtin_amdgcn_mfma_f32_16x16x32_bf16(af[i], bf[j], acc[i][j], 0, 0, 0);
    }
    __syncthreads();
  }

  // epilogue: C/D layout col=lane&15 (N), row=(lane>>4)*4+r (M); store bf16
  const int region = blockIdx.y >> 2;       // 0=z(tanh) 1=f(sig) 2=o(sig)
  const int rowB = wr * 64 + (lane >> 4) * 4;
  const int colB = wc * 64 + (lane & 15);
#pragma unroll
  for (int i = 0; i < 4; i++)
#pragma unroll
    for (int j = 0; j < 4; j++)
#pragma unroll
      for (int r = 0; r < 4; r++) {
        int mm = m0 + rowB + i * 16 + r;
        int nn = n0 + colB + j * 16;
        float g = acc[i][j][r] + bias[nn];
        float a = (region == 0) ? fast_tanh(g) : fast_sigmoid(g);
        gates[(size_t)mm * Nn + nn] = f2bf(a);
      }
}

// ---- 4. per-chunk affine (a, bv): h_end = a*h_start + bv --------------------
// grid 512 = (chunk, half-of-u); 256 threads
__global__ __launch_bounds__(256) void scan_phaseA(const unsigned short* __restrict__ gates,
                                                   float* __restrict__ aArr,
                                                   float* __restrict__ bArr) {
  int chunk = blockIdx.x >> 1;
  int u = (blockIdx.x & 1) * 256 + threadIdx.x;
  int b = chunk >> 5, c = chunk & (NC - 1);
  const unsigned short* gp = gates + (size_t)(b * Tn + c * CL) * Nn;
  float a = 1.0f, bv = 0.0f;
#pragma unroll 4
  for (int t = 0; t < CL; t++) {
    float z = bf2f(gp[u]);
    float f = bf2f(gp[Un + u]);
    a *= f;
    bv = f * bv + (1.0f - f) * z;
    gp += Nn;
  }
  aArr[(size_t)chunk * Un + u] = a;
  bArr[(size_t)chunk * Un + u] = bv;
}

// ---- 5. scan over chunks ----------------------------------------------------
__global__ __launch_bounds__(256) void scan_phaseB(const float* __restrict__ aArr,
                                                   const float* __restrict__ bArr,
                                                   const float* __restrict__ init,
                                                   float* __restrict__ hstart) {
  int idx = blockIdx.x * 256 + threadIdx.x; // 0..4095 = (b,u)
  int b = idx >> 9, u = idx & (Un - 1);
  float h = init[u];
  for (int c = 0; c < NC; c++) {
    size_t offc = (size_t)(b * NC + c) * Un + u;
    hstart[offc] = h;
    h = aArr[offc] * h + bArr[offc];
  }
}

// ---- 6. replay chunk with known h_start, apply output gate ------------------
__global__ __launch_bounds__(256) void scan_phaseC(const unsigned short* __restrict__ gates,
                                                   const float* __restrict__ hstart,
                                                   float* __restrict__ out) {
  int chunk = blockIdx.x >> 1;
  int u = (blockIdx.x & 1) * 256 + threadIdx.x;
  int b = chunk >> 5, c = chunk & (NC - 1);
  const unsigned short* gp = gates + (size_t)(b * Tn + c * CL) * Nn;
  float* op = out + (size_t)(b * Tn + c * CL) * Un;
  float h = hstart[(size_t)chunk * Un + u];
#pragma unroll 4
  for (int t = 0; t < CL; t++) {
    float z = bf2f(gp[u]);
    float f = bf2f(gp[Un + u]);
    float o = bf2f(gp[2 * Un + u]);
    h = f * h + (1.0f - f) * z;
    op[u] = h * o;
    gp += Nn;
    op += Un;
  }
}

extern "C" void kernel_launch(void* const* d_in, const int* in_sizes, int n_in,
                              void* d_out, int out_size, void* d_ws, size_t ws_size,
                              hipStream_t stream) {
  const float* x    = (const float*)d_in[0];  // [8,2048,512]
  const float* kern = (const float*)d_in[1];  // [2,512,1536]
  const float* bias = (const float*)d_in[2];  // [1536]
  const float* init = (const float*)d_in[3];  // [1,512]
  float* out = (float*)d_out;                 // [8,2048,512]

  char* ws = (char*)d_ws;
  unsigned short* xb = (unsigned short*)ws;                      // 16.8 MB
  size_t off = (size_t)Bn * (Tn + 1) * Cn * 2;
  unsigned short* kT = (unsigned short*)(ws + off);              // 3.1 MB
  off += (size_t)Nn * Kn * 2;
  unsigned short* gates = (unsigned short*)(ws + off);           // 50.3 MB (bf16)
  off += (size_t)Mn * Nn * 2;
  float* aArr = (float*)(ws + off);  off += (size_t)Bn * NC * Un * 4;
  float* bArr = (float*)(ws + off);  off += (size_t)Bn * NC * Un * 4;
  float* hstart = (float*)(ws + off);

  conv_x<<<(Bn * (Tn + 1) * Cn / 4) / 256, 256, 0, stream>>>(x, xb);
  conv_k<<<dim3(32, 48), 256, 0, stream>>>(kern, kT);
  gemm_gates<<<dim3(Mn / 128, Nn / 128), 256, 0, stream>>>(xb, kT, bias, gates);
  scan_phaseA<<<Bn * NC * 2, 256, 0, stream>>>(gates, aArr, bArr);
  scan_phaseB<<<(Bn * Un) / 256, 256, 0, stream>>>(aArr, bArr, init, hstart);
  scan_phaseC<<<Bn * NC * 2, 256, 0, stream>>>(gates, hstart, out);
}